// Round 1
// baseline (85.660 us; speedup 1.0000x reference)
//
#include <hip/hip_runtime.h>
#include <hip/hip_bf16.h>
#include <math.h>

#define B_DIM 16
#define T_DIM 100
#define TPAD 112            // 7 MFMA row-tiles of 16
#define HW_PIX (27 * 48)    // 1296 pixels/frame
#define NBINS 512
#define WIN 101
#define HALF 50
#define ODIM 128
#define NTILE 7             // TPAD/16
#define SSTRIDE 132         // S-block row stride in LDS (132%32=4 -> only 2-way conflicts)

typedef __attribute__((ext_vector_type(8))) short s16x8;
typedef __attribute__((ext_vector_type(4))) float f32x4;

// ---------------------------------------------------------------------------
// Kernel A: per-frame 512-bin histogram, L2-normalized, stored bf16 into
// X16[b][t][512] with rows 100..111 zeroed (MFMA padding + zero-row for
// out-of-range band columns).
// blocks 0..1599: one frame each. blocks 1600..1791: zero one pad row each.
// ---------------------------------------------------------------------------
__global__ __launch_bounds__(256) void hist_kernel(
    const int* __restrict__ frames, __hip_bfloat16* __restrict__ X16) {
  const int bid = blockIdx.x;
  const int tid = threadIdx.x;

  if (bid >= B_DIM * T_DIM) {
    // zero a pad row: rows (b*112 + 100..111)
    const int pid = bid - B_DIM * T_DIM;      // 0..191
    const int b = pid / (TPAD - T_DIM);
    const int r = pid - b * (TPAD - T_DIM);
    unsigned int* row = (unsigned int*)(X16 + ((size_t)(b * TPAD + T_DIM + r)) * NBINS);
    row[tid] = 0u;                             // 256 uints = 512 bf16
    return;
  }

  __shared__ int h[NBINS];
  __shared__ float red[16];

  for (int i = tid; i < NBINS; i += 256) h[i] = 0;
  __syncthreads();

  // 1296 pixels = 324 groups of 4 pixels (12 dwords = 3 int4 loads)
  const int* fp = frames + (size_t)bid * (HW_PIX * 3);
  for (int i = tid; i < HW_PIX / 4; i += 256) {
    const int4* q = (const int4*)(fp + 12 * i);
    int4 a = q[0], c = q[1], e = q[2];
    int b0 = ((a.x >> 5) << 6) + ((a.y >> 5) << 3) + (a.z >> 5);
    int b1 = ((a.w >> 5) << 6) + ((c.x >> 5) << 3) + (c.y >> 5);
    int b2 = ((c.z >> 5) << 6) + ((c.w >> 5) << 3) + (e.x >> 5);
    int b3 = ((e.y >> 5) << 6) + ((e.z >> 5) << 3) + (e.w >> 5);
    atomicAdd(&h[b0], 1);
    atomicAdd(&h[b1], 1);
    atomicAdd(&h[b2], 1);
    atomicAdd(&h[b3], 1);
  }
  __syncthreads();

  float ss = 0.f;
  for (int i = tid; i < NBINS; i += 256) {
    float v = (float)h[i];
    ss += v * v;
  }
  const int lane = tid & 63, wave = tid >> 6;
#pragma unroll
  for (int off = 32; off > 0; off >>= 1) ss += __shfl_down(ss, off);
  if (lane == 0) red[wave] = ss;
  __syncthreads();
  if (tid == 0) red[8] = 1.0f / sqrtf(red[0] + red[1] + red[2] + red[3]);
  __syncthreads();
  const float rn = red[8];

  const int b = bid / T_DIM;
  const int t = bid - b * T_DIM;
  __hip_bfloat16* row = X16 + ((size_t)(b * TPAD + t)) * NBINS;
  for (int i = tid; i < NBINS; i += 256) row[i] = __float2bfloat16((float)h[i] * rn);
}

// ---------------------------------------------------------------------------
// Kernel B (fused sim + band + FC):
// Grid = 16 batches * 7 chunks of 16 t's; 256 threads (4 waves).
// Phase 1: each wave computes 2 column-tiles of S[16][128] where
//   S[m][n] = dot(X[t0+m], X[t0-50+n])  via mfma_f32_16x16x32_bf16,
//   reading fragments straight from L2-resident X16 (no LDS staging).
//   Out-of-range rows (s<0 or s>=100) clamp to the zeroed pad row 100.
// Phase 2: band[tl][j] = S[tl][tl+j]; FC(101->128) + ReLU in f32 (as before).
// LDS: fc_w (101x128 f32, 51712 B) + S (16 x 132 f32, 8448 B) = 60160 B.
// ---------------------------------------------------------------------------
__global__ __launch_bounds__(256) void simfc_kernel(
    const __hip_bfloat16* __restrict__ X16, const float* __restrict__ fc_w,
    const float* __restrict__ fc_b, float* __restrict__ out) {
  __shared__ __align__(16) float wlds[WIN * ODIM];   // 51712 B
  __shared__ __align__(16) float slds[16 * SSTRIDE]; // 8448 B

  const int cid = blockIdx.x;
  const int b = cid / NTILE;
  const int t0 = (cid - b * NTILE) * 16;
  const int tid = threadIdx.x;

  // stage fc_w as float4 (consumed after the barrier; overlaps MFMA issue)
  {
    const f32x4* src = (const f32x4*)fc_w;
    f32x4* dst = (f32x4*)wlds;
    for (int i = tid; i < (WIN * ODIM) / 4; i += 256) dst[i] = src[i];
  }

  // ---- Phase 1: MFMA S-block ----
  const int lane = tid & 63, wv = tid >> 6;
  const int m16 = lane & 15, quad = lane >> 4;

  // A rows t0+m16 <= 96+15 = 111 < TPAD: always in-bounds (pad rows are zero).
  const short* Abase =
      (const short*)(X16 + ((size_t)(b * TPAD + t0 + m16)) * NBINS) + quad * 8;
  // zero row (row 100 of this batch, zeroed by hist pad blocks)
  const short* zrow =
      (const short*)(X16 + ((size_t)(b * TPAD + T_DIM)) * NBINS) + quad * 8;

  // wave wv owns columns n in [wv*32, wv*32+31] (two 16-wide n-tiles)
  const int s0 = t0 - HALF + wv * 32 + m16;
  const int s1 = s0 + 16;
  const short* B0 = (s0 >= 0 && s0 < T_DIM)
      ? (const short*)(X16 + ((size_t)(b * TPAD + s0)) * NBINS) + quad * 8
      : zrow;
  const short* B1 = (s1 >= 0 && s1 < T_DIM)
      ? (const short*)(X16 + ((size_t)(b * TPAD + s1)) * NBINS) + quad * 8
      : zrow;

  f32x4 acc0 = {0.f, 0.f, 0.f, 0.f};
  f32x4 acc1 = {0.f, 0.f, 0.f, 0.f};
#pragma unroll 4
  for (int k = 0; k < NBINS; k += 32) {
    s16x8 af = *(const s16x8*)(Abase + k);
    s16x8 bf0 = *(const s16x8*)(B0 + k);
    s16x8 bf1 = *(const s16x8*)(B1 + k);
    acc0 = __builtin_amdgcn_mfma_f32_16x16x32_bf16(af, bf0, acc0, 0, 0, 0);
    acc1 = __builtin_amdgcn_mfma_f32_16x16x32_bf16(af, bf1, acc1, 0, 0, 0);
  }

  // D layout: col = lane&15, row = quad*4 + r. Write S[m][n] to LDS.
#pragma unroll
  for (int r = 0; r < 4; ++r) {
    slds[(quad * 4 + r) * SSTRIDE + wv * 32 + m16] = acc0[r];
    slds[(quad * 4 + r) * SSTRIDE + wv * 32 + 16 + m16] = acc1[r];
  }
  __syncthreads();

  // ---- Phase 2: FC. band[tl][j] = S[tl][tl+j] (max col 15+100=115 < 128) ----
  const int g4 = tid & 31;        // d = 4*g4 .. 4*g4+3
  const int tl0 = tid >> 5;       // 0..7
  const int tl1 = tl0 + 8;

  f32x4 accA = ((const f32x4*)fc_b)[g4];
  f32x4 accB = accA;
#pragma unroll 4
  for (int j = 0; j < WIN; ++j) {
    f32x4 w4 = *(const f32x4*)&wlds[j * ODIM + g4 * 4];
    float v0 = slds[tl0 * SSTRIDE + tl0 + j];
    float v1 = slds[tl1 * SSTRIDE + tl1 + j];
    accA += w4 * v0;
    accB += w4 * v1;
  }

#pragma unroll
  for (int c = 0; c < 4; ++c) {
    accA[c] = fmaxf(accA[c], 0.f);
    accB[c] = fmaxf(accB[c], 0.f);
  }

  const int ta = t0 + tl0, tb = t0 + tl1;
  if (ta < T_DIM)
    *(f32x4*)&out[((size_t)b * T_DIM + ta) * ODIM + g4 * 4] = accA;
  if (tb < T_DIM)
    *(f32x4*)&out[((size_t)b * T_DIM + tb) * ODIM + g4 * 4] = accB;
}

extern "C" void kernel_launch(void* const* d_in, const int* in_sizes, int n_in,
                              void* d_out, int out_size, void* d_ws, size_t ws_size,
                              hipStream_t stream) {
  const int* frames = (const int*)d_in[0];     // (16,100,27,48,3) int32
  const float* fc_w = (const float*)d_in[1];   // (101,128) f32
  const float* fc_b = (const float*)d_in[2];   // (128,) f32
  float* out = (float*)d_out;                  // (16,100,128) f32

  __hip_bfloat16* X16 = (__hip_bfloat16*)d_ws; // 16*112*512 bf16 = 1.835 MB

  hist_kernel<<<B_DIM * T_DIM + B_DIM * (TPAD - T_DIM), 256, 0, stream>>>(frames, X16);
  simfc_kernel<<<B_DIM * NTILE, 256, 0, stream>>>(X16, fc_w, fc_b, out);
}

// Round 2
// 85.528 us; speedup vs baseline: 1.0015x; 1.0015x over previous
//
#include <hip/hip_runtime.h>
#include <hip/hip_bf16.h>
#include <math.h>

#define B_DIM 16
#define T_DIM 100
#define TPAD 112            // 7 MFMA row-tiles of 16
#define HW_PIX (27 * 48)    // 1296 pixels/frame
#define NBINS 512
#define WIN 101
#define HALF 50
#define ODIM 128
#define NTILE 7             // TPAD/16
#define SSTRIDE 132         // S-block row stride in LDS (132%32=4 -> only 2-way conflicts)

typedef __attribute__((ext_vector_type(8))) short s16x8;
typedef __attribute__((ext_vector_type(4))) float f32x4;

// ---------------------------------------------------------------------------
// Kernel A: per-frame 512-bin histogram, L2-normalized, stored bf16 into
// X16[b][t][512]. Only row 100 of each batch needs zeroing (it is the
// clamp target for out-of-range band columns in the MFMA B-operand);
// rows 101..111 feed only discarded output rows, so they may stay poison.
// Grid = 1600 blocks (one frame each); blocks with t==0 also zero row 100.
// ---------------------------------------------------------------------------
__global__ __launch_bounds__(256) void hist_kernel(
    const int* __restrict__ frames, __hip_bfloat16* __restrict__ X16) {
  const int bid = blockIdx.x;
  const int tid = threadIdx.x;
  const int b = bid / T_DIM;
  const int t = bid - b * T_DIM;

  __shared__ int h[NBINS];
  __shared__ float red[16];

  for (int i = tid; i < NBINS; i += 256) h[i] = 0;

  // fold pad-row zeroing into the t==0 block (one zero row per batch)
  if (t == 0) {
    unsigned int* zr = (unsigned int*)(X16 + ((size_t)(b * TPAD + T_DIM)) * NBINS);
    zr[tid] = 0u;                              // 256 dwords = 512 bf16
  }
  __syncthreads();

  // 1296 pixels = 324 groups of 4 pixels (12 dwords = 3 int4 loads)
  const int* fp = frames + (size_t)bid * (HW_PIX * 3);
  for (int i = tid; i < HW_PIX / 4; i += 256) {
    const int4* q = (const int4*)(fp + 12 * i);
    int4 a = q[0], c = q[1], e = q[2];
    int b0 = ((a.x >> 5) << 6) + ((a.y >> 5) << 3) + (a.z >> 5);
    int b1 = ((a.w >> 5) << 6) + ((c.x >> 5) << 3) + (c.y >> 5);
    int b2 = ((c.z >> 5) << 6) + ((c.w >> 5) << 3) + (e.x >> 5);
    int b3 = ((e.y >> 5) << 6) + ((e.z >> 5) << 3) + (e.w >> 5);
    atomicAdd(&h[b0], 1);
    atomicAdd(&h[b1], 1);
    atomicAdd(&h[b2], 1);
    atomicAdd(&h[b3], 1);
  }
  __syncthreads();

  float ss = 0.f;
  for (int i = tid; i < NBINS; i += 256) {
    float v = (float)h[i];
    ss += v * v;
  }
  const int lane = tid & 63, wave = tid >> 6;
#pragma unroll
  for (int off = 32; off > 0; off >>= 1) ss += __shfl_down(ss, off);
  if (lane == 0) red[wave] = ss;
  __syncthreads();
  if (tid == 0) red[8] = 1.0f / sqrtf(red[0] + red[1] + red[2] + red[3]);
  __syncthreads();
  const float rn = red[8];

  // packed store: thread tid writes bins {2*tid, 2*tid+1} as one dword
  {
    unsigned int lo = (unsigned int)__bfloat16_as_ushort(
        __float2bfloat16((float)h[2 * tid] * rn));
    unsigned int hi = (unsigned int)__bfloat16_as_ushort(
        __float2bfloat16((float)h[2 * tid + 1] * rn));
    unsigned int* row =
        (unsigned int*)(X16 + ((size_t)(b * TPAD + t)) * NBINS);
    row[tid] = lo | (hi << 16);
  }
}

// ---------------------------------------------------------------------------
// Kernel B (fused sim + band + FC):
// Grid = 16 batches * 7 chunks of 16 t's; 256 threads (4 waves).
// Phase 1: each wave computes 2 column-tiles of S[16][128] where
//   S[m][n] = dot(X[t0+m], X[t0-50+n])  via mfma_f32_16x16x32_bf16,
//   reading fragments straight from L2-resident X16 (no LDS staging).
//   Out-of-range rows (s<0 or s>=100) clamp to the zeroed row 100.
// Phase 2: band[tl][j] = S[tl][tl+j]; FC(101->128) + ReLU in f32.
// LDS: fc_w (101x128 f32, 51712 B) + S (16 x 132 f32, 8448 B) = 60160 B.
// ---------------------------------------------------------------------------
__global__ __launch_bounds__(256) void simfc_kernel(
    const __hip_bfloat16* __restrict__ X16, const float* __restrict__ fc_w,
    const float* __restrict__ fc_b, float* __restrict__ out) {
  __shared__ __align__(16) float wlds[WIN * ODIM];   // 51712 B
  __shared__ __align__(16) float slds[16 * SSTRIDE]; // 8448 B

  const int cid = blockIdx.x;
  const int b = cid / NTILE;
  const int t0 = (cid - b * NTILE) * 16;
  const int tid = threadIdx.x;

  // stage fc_w as float4 (consumed after the barrier; overlaps MFMA issue)
  {
    const f32x4* src = (const f32x4*)fc_w;
    f32x4* dst = (f32x4*)wlds;
    for (int i = tid; i < (WIN * ODIM) / 4; i += 256) dst[i] = src[i];
  }

  // ---- Phase 1: MFMA S-block ----
  const int lane = tid & 63, wv = tid >> 6;
  const int m16 = lane & 15, quad = lane >> 4;

  // A rows t0+m16 <= 96+15 = 111 < TPAD: always in-bounds (pad rows feed
  // only discarded outputs).
  const short* Abase =
      (const short*)(X16 + ((size_t)(b * TPAD + t0 + m16)) * NBINS) + quad * 8;
  // zero row (row 100 of this batch, zeroed by the t==0 hist block)
  const short* zrow =
      (const short*)(X16 + ((size_t)(b * TPAD + T_DIM)) * NBINS) + quad * 8;

  // wave wv owns columns n in [wv*32, wv*32+31] (two 16-wide n-tiles)
  const int s0 = t0 - HALF + wv * 32 + m16;
  const int s1 = s0 + 16;
  const short* B0 = (s0 >= 0 && s0 < T_DIM)
      ? (const short*)(X16 + ((size_t)(b * TPAD + s0)) * NBINS) + quad * 8
      : zrow;
  const short* B1 = (s1 >= 0 && s1 < T_DIM)
      ? (const short*)(X16 + ((size_t)(b * TPAD + s1)) * NBINS) + quad * 8
      : zrow;

  f32x4 acc0 = {0.f, 0.f, 0.f, 0.f};
  f32x4 acc1 = {0.f, 0.f, 0.f, 0.f};
#pragma unroll 8
  for (int k = 0; k < NBINS; k += 32) {
    s16x8 af = *(const s16x8*)(Abase + k);
    s16x8 bf0 = *(const s16x8*)(B0 + k);
    s16x8 bf1 = *(const s16x8*)(B1 + k);
    acc0 = __builtin_amdgcn_mfma_f32_16x16x32_bf16(af, bf0, acc0, 0, 0, 0);
    acc1 = __builtin_amdgcn_mfma_f32_16x16x32_bf16(af, bf1, acc1, 0, 0, 0);
  }

  // D layout: col = lane&15, row = quad*4 + r. Write S[m][n] to LDS.
  // Bank check: row stride 132 (mod 32 = 4); within a wave rows step by 4
  // (528 B, bank shift 16) -> quads {0,2} and {1,3} hit disjoint bank
  // halves -> only 2-way aliasing (free).
#pragma unroll
  for (int r = 0; r < 4; ++r) {
    slds[(quad * 4 + r) * SSTRIDE + wv * 32 + m16] = acc0[r];
    slds[(quad * 4 + r) * SSTRIDE + wv * 32 + 16 + m16] = acc1[r];
  }
  __syncthreads();

  // ---- Phase 2: FC. band[tl][j] = S[tl][tl+j] (max col 15+100=115 < 128) ----
  const int g4 = tid & 31;        // d = 4*g4 .. 4*g4+3
  const int tl0 = tid >> 5;       // 0..7
  const int tl1 = tl0 + 8;

  f32x4 accA = ((const f32x4*)fc_b)[g4];
  f32x4 accB = accA;
#pragma unroll 4
  for (int j = 0; j < WIN; ++j) {
    f32x4 w4 = *(const f32x4*)&wlds[j * ODIM + g4 * 4];
    float v0 = slds[tl0 * SSTRIDE + tl0 + j];
    float v1 = slds[tl1 * SSTRIDE + tl1 + j];
    accA += w4 * v0;
    accB += w4 * v1;
  }

#pragma unroll
  for (int c = 0; c < 4; ++c) {
    accA[c] = fmaxf(accA[c], 0.f);
    accB[c] = fmaxf(accB[c], 0.f);
  }

  const int ta = t0 + tl0, tb = t0 + tl1;
  if (ta < T_DIM)
    *(f32x4*)&out[((size_t)b * T_DIM + ta) * ODIM + g4 * 4] = accA;
  if (tb < T_DIM)
    *(f32x4*)&out[((size_t)b * T_DIM + tb) * ODIM + g4 * 4] = accB;
}

extern "C" void kernel_launch(void* const* d_in, const int* in_sizes, int n_in,
                              void* d_out, int out_size, void* d_ws, size_t ws_size,
                              hipStream_t stream) {
  const int* frames = (const int*)d_in[0];     // (16,100,27,48,3) int32
  const float* fc_w = (const float*)d_in[1];   // (101,128) f32
  const float* fc_b = (const float*)d_in[2];   // (128,) f32
  float* out = (float*)d_out;                  // (16,100,128) f32

  __hip_bfloat16* X16 = (__hip_bfloat16*)d_ws; // 16*112*512 bf16 = 1.835 MB

  hist_kernel<<<B_DIM * T_DIM, 256, 0, stream>>>(frames, X16);
  simfc_kernel<<<B_DIM * NTILE, 256, 0, stream>>>(X16, fc_w, fc_b, out);
}